// Round 15
// baseline (185.133 us; speedup 1.0000x reference)
//
#include <hip/hip_runtime.h>
#include <hip/hip_bf16.h>

// Fused MHA forward (B=8, I=J=1024, WIDTH=512, NH=8, HD=64), fp32 in/out.
// R15 = R14 + ONE change: attention K is read DIRECTLY from global as 16B
// bf16x8 frags (per-lane j=lane&15, d-run contiguous) -- K-LDS staging and
// all pass-A barriers eliminated. Pass A: pure dataflow (loads+MFMA+exp).
// Pass B: only V staged (dbuf, 8 barriers, counted vmcnt). LDS 80->48KB.

typedef __hip_bfloat16 bf16;
typedef __attribute__((ext_vector_type(8))) short bf16x8;   // MFMA A/B frag (4 VGPR)
typedef __attribute__((ext_vector_type(4))) float f32x4;    // MFMA C/D frag, nt-store vec

#define BATCH 8
#define SEQ   1024
#define WIDTH 512
#define NHEAD 8
#define HD    64
#define SCALE_F 0.044194173824159216f     // 512^-0.5 (width, per reference!)

static __device__ __forceinline__ unsigned short f2bf(float x) {
  union { float f; unsigned u; } a; a.f = x;
  unsigned r = a.u + 0x7fffu + ((a.u >> 16) & 1u);   // RNE
  return (unsigned short)(r >> 16);
}
static __device__ __forceinline__ float bf2f(unsigned short u) {
  union { unsigned u; float f; } a; a.u = ((unsigned)u) << 16; return a.f;
}

static __device__ __forceinline__ void gload_lds16(const void* g, void* l) {
  __builtin_amdgcn_global_load_lds((const __attribute__((address_space(1))) void*)g,
                                   (__attribute__((address_space(3))) void*)l,
                                   16, 0, 0);
}

// Swizzled LDS tile: rows of 64 bf16 (128B); 16B-unit phys col = logical ^ (row&7).
static __device__ __forceinline__ bf16x8 frag_ld(const short* tile, int row, int c16) {
  int p = c16 ^ (row & 7);
  return *(const bf16x8*)(tile + row*64 + p*8);
}

// ---------------- cast fp32 -> bf16 (q,k,v + 4 weights) ----------------
__global__ void cast_all_kernel(const float* __restrict__ q, const float* __restrict__ k,
                                const float* __restrict__ v, const float* __restrict__ wq,
                                const float* __restrict__ wk, const float* __restrict__ wv,
                                const float* __restrict__ wo, bf16* __restrict__ wsb) {
  const long NQ = 1048576;   // float4 groups per q/k/v (8192*512/4)
  const long NW = 65536;     // per weight (512*512/4)
  long g = (long)blockIdx.x * blockDim.x + threadIdx.x;
  const float* src; bf16* dst; long o;
  if (g < 3*NQ) {
    int t = (int)(g / NQ); o = g - (long)t*NQ;
    src = (t==0) ? q : ((t==1) ? k : v);
    dst = wsb + (size_t)t * 4194304;
  } else {
    long g2 = g - 3*NQ;
    if (g2 >= 4*NW) return;
    int t = (int)(g2 / NW); o = g2 - (long)t*NW;
    src = (t==0) ? wq : ((t==1) ? wk : ((t==2) ? wv : wo));
    dst = wsb + (size_t)3*4194304 + (size_t)t * 262144;
  }
  float4 f = ((const float4*)src)[o];
  ushort4 r4;
  r4.x = f2bf(f.x); r4.y = f2bf(f.y); r4.z = f2bf(f.z); r4.w = f2bf(f.w);
  ((ushort4*)dst)[o] = r4;
}

// ---------------- QKV GEMM: C[8192][512] = A @ W^T (merged q,k,v) ----------------
__global__ __launch_bounds__(256) void gemm_qkv(const bf16* __restrict__ A0, const bf16* __restrict__ A1,
                                                const bf16* __restrict__ A2, const bf16* __restrict__ W0,
                                                const bf16* __restrict__ W1, const bf16* __restrict__ W2,
                                                bf16* __restrict__ C0, bf16* __restrict__ C1,
                                                bf16* __restrict__ C2) {
  __shared__ short As[2][128*64];
  __shared__ short Bs[2][128*64];

  const int bid = blockIdx.x;               // 768 blocks
  const int xcd = bid & 7;
  const int idx = bid >> 3;                 // 0..95
  const int g   = xcd*24 + (idx >> 2);      // 0..191
  const int y   = idx & 3;
  const int z   = g >> 6;                   // 0:q 1:k 2:v
  const int m   = g & 63;

  const bf16* A  = (z==0) ? A0 : ((z==1) ? A1 : A2);
  const bf16* Bw = (z==0) ? W0 : ((z==1) ? W1 : W2);
  bf16* Cout     = (z==0) ? C0 : ((z==1) ? C1 : C2);

  const int lane = threadIdx.x & 63;
  const int wid  = threadIdx.x >> 6;
  const int m0 = m * 128;
  const int n0 = y * 128;
  const int wm = (wid >> 1) * 64;
  const int wn = (wid & 1) * 64;
  const int lrow = lane >> 3;
  const int swz  = ((lane & 7) ^ lrow) * 8;

  const f32x4 zero4 = {0.f,0.f,0.f,0.f};
  f32x4 acc[4][4];
  for (int i=0;i<4;++i) for (int j=0;j<4;++j) acc[i][j] = zero4;

  auto stage = [&](int buf, int t) {
    const int k0 = t * 64;
    for (int i = 0; i < 4; ++i) {
      int c = wid*4 + i;
      int row = c*8 + lrow;
      gload_lds16(A  + (size_t)(m0 + row)*WIDTH + k0 + swz, &As[buf][c*512]);
      gload_lds16(Bw + (size_t)(n0 + row)*WIDTH + k0 + swz, &Bs[buf][c*512]);
    }
  };

  stage(0, 0);
  asm volatile("s_waitcnt vmcnt(0)" ::: "memory");
  __syncthreads();
  int cur = 0;

  for (int t = 0; t < 8; ++t) {
    if (t < 7) stage(cur ^ 1, t + 1);
    for (int kc = 0; kc < 2; ++kc) {
      bf16x8 af[4], bfr[4];
      for (int mf=0; mf<4; ++mf) af[mf]  = frag_ld(&As[cur][0], wm + mf*16 + (lane&15), (lane>>4) + kc*4);
      for (int nf=0; nf<4; ++nf) bfr[nf] = frag_ld(&Bs[cur][0], wn + nf*16 + (lane&15), (lane>>4) + kc*4);
      for (int mf=0; mf<4; ++mf)
        for (int nf=0; nf<4; ++nf)
          acc[mf][nf] = __builtin_amdgcn_mfma_f32_16x16x32_bf16(af[mf], bfr[nf], acc[mf][nf], 0,0,0);
    }
    if (t < 7) {
      asm volatile("s_waitcnt vmcnt(0)" ::: "memory");
      __syncthreads();
      cur ^= 1;
    }
  }
  for (int mf=0; mf<4; ++mf)
    for (int nf=0; nf<4; ++nf) {
      int col = n0 + wn + nf*16 + (lane & 15);
      for (int r=0; r<4; ++r) {
        int row = m0 + wm + mf*16 + (lane>>4)*4 + r;
        ((unsigned short*)Cout)[(size_t)row*WIDTH + col] = f2bf(acc[mf][nf][r]);
      }
    }
}

// ---------------- output GEMM: x[8192][512] = ctx @ Wo^T, fp32 nt out ----------------
__global__ __launch_bounds__(256) void gemm_out(const bf16* __restrict__ A,
                                                const bf16* __restrict__ Bw,
                                                float* __restrict__ Cout) {
  __shared__ short As[2][128*64];
  __shared__ short Bs[2][64*64];

  const int bid = blockIdx.x;                // 512 blocks
  const int xcd = bid & 7;
  const int idx = bid >> 3;                  // 0..63
  const int m   = xcd*8 + (idx >> 3);        // 0..63
  const int y   = idx & 7;                   // 0..7 (64-col panels)

  const int lane = threadIdx.x & 63;
  const int wid  = threadIdx.x >> 6;
  const int m0 = m * 128;
  const int n0 = y * 64;
  const int wm = (wid >> 1) * 64;
  const int wn = (wid & 1) * 32;
  const int lrow = lane >> 3;
  const int swz  = ((lane & 7) ^ lrow) * 8;

  const f32x4 zero4 = {0.f,0.f,0.f,0.f};
  f32x4 acc[4][2];
  for (int i=0;i<4;++i) for (int j=0;j<2;++j) acc[i][j] = zero4;

  auto stage = [&](int buf, int t) {
    const int k0 = t * 64;
    for (int i = 0; i < 4; ++i) {
      int c = wid*4 + i;
      int row = c*8 + lrow;
      gload_lds16(A + (size_t)(m0 + row)*WIDTH + k0 + swz, &As[buf][c*512]);
    }
    for (int i = 0; i < 2; ++i) {
      int c = wid*2 + i;
      int row = c*8 + lrow;
      gload_lds16(Bw + (size_t)(n0 + row)*WIDTH + k0 + swz, &Bs[buf][c*512]);
    }
  };

  stage(0, 0);
  asm volatile("s_waitcnt vmcnt(0)" ::: "memory");
  __syncthreads();
  int cur = 0;

  for (int t = 0; t < 8; ++t) {
    if (t < 7) stage(cur ^ 1, t + 1);
    for (int kc = 0; kc < 2; ++kc) {
      bf16x8 af[4], bfr[2];
      for (int mf=0; mf<4; ++mf) af[mf]  = frag_ld(&As[cur][0], wm + mf*16 + (lane&15), (lane>>4) + kc*4);
      for (int nf=0; nf<2; ++nf) bfr[nf] = frag_ld(&Bs[cur][0], wn + nf*16 + (lane&15), (lane>>4) + kc*4);
      for (int mf=0; mf<4; ++mf)
        for (int nf=0; nf<2; ++nf)
          acc[mf][nf] = __builtin_amdgcn_mfma_f32_16x16x32_bf16(af[mf], bfr[nf], acc[mf][nf], 0,0,0);
    }
    if (t < 7) {
      asm volatile("s_waitcnt vmcnt(0)" ::: "memory");
      __syncthreads();
      cur ^= 1;
    }
  }
  for (int mf=0; mf<4; ++mf)
    for (int nf=0; nf<2; ++nf) {
      int col = n0 + wn + nf*16 + (lane & 15);
      for (int r=0; r<4; ++r) {
        int row = m0 + wm + mf*16 + (lane>>4)*4 + r;
        __builtin_nontemporal_store(acc[mf][nf][r], Cout + (size_t)row*WIDTH + col);
      }
    }
}

// ---------------- V transpose: per head (1024,64) -> (64,1024) ----------------
__global__ __launch_bounds__(256) void transpose_v(const bf16* __restrict__ Vh,
                                                   bf16* __restrict__ Vt) {
  __shared__ short t[64][72];
  int h  = blockIdx.x >> 4;
  int j0 = (blockIdx.x & 15) * 64;
  const bf16* src = Vh + (size_t)h * (SEQ*HD);
  bf16* dst = Vt + (size_t)h * (SEQ*HD);
  int tid = threadIdx.x;
  int r  = tid >> 2;
  int c0 = (tid & 3) * 16;
  bf16x8 v0 = *(const bf16x8*)(src + (size_t)(j0 + r)*HD + c0);
  bf16x8 v1 = *(const bf16x8*)(src + (size_t)(j0 + r)*HD + c0 + 8);
  for (int i = 0; i < 8; ++i) { t[r][c0+i] = v0[i]; t[r][c0+8+i] = v1[i]; }
  __syncthreads();
  bf16x8 w0, w1;
  for (int i = 0; i < 8; ++i) { w0[i] = t[c0+i][r]; w1[i] = t[c0+8+i][r]; }
  *(bf16x8*)(dst + (size_t)r*SEQ + j0 + c0)     = w0;
  *(bf16x8*)(dst + (size_t)r*SEQ + j0 + c0 + 8) = w1;
}

// ---------------- fused attention (2-pass, direct-global K) ----------------
// Block = 8 waves x 16 rows = 128 q-rows of one head; XCD-chunked (8 heads/XCD).
// K frags are 16B global loads (j=lane&15, d contiguous) -- no K staging.
// Pass A: barrier-free dataflow. Pass B: V-only LDS dbuf (KVBLK=128, 8
// barriers, counted vmcnt); Ws stash feeds PV + vectorized nt attn_out stores.
__global__ __launch_bounds__(512) void attn_kernel(const bf16* __restrict__ Qh,
                                                   const bf16* __restrict__ Kh,
                                                   const bf16* __restrict__ Vt,
                                                   float* __restrict__ attn_out,
                                                   bf16* __restrict__ ctx) {
  __shared__ short Vs[2][128*64];    // 2 sub-tiles [d 0..63][j half*64..+63]
  __shared__ short Ws[8][16*64];

  const int lane = threadIdx.x & 63;
  const int wid  = threadIdx.x >> 6;         // 0..7
  const int bid  = blockIdx.x;
  const int xcd  = bid & 7;
  const int idx  = bid >> 3;                 // 0..63
  const int h    = xcd*8 + (idx >> 3);       // 8 heads/XCD
  const int i0   = (idx & 7) * 128;
  const int b  = h >> 3;
  const int nh = h & 7;

  const bf16* Qhead  = Qh + (size_t)h * (SEQ*HD);
  const bf16* Khead  = Kh + (size_t)h * (SEQ*HD);
  const bf16* Vthead = Vt + (size_t)h * (SEQ*HD);

  const int lrow = lane >> 3;
  const int swz  = ((lane & 7) ^ lrow) * 8;

  const int qrow = i0 + wid*16 + (lane & 15);
  bf16x8 qf[2];
  qf[0] = *(const bf16x8*)(Qhead + (size_t)qrow*HD + (lane>>4)*8);
  qf[1] = *(const bf16x8*)(Qhead + (size_t)qrow*HD + 32 + (lane>>4)*8);

  const f32x4 zero4 = {0.f,0.f,0.f,0.f};
  const int kjl = lane & 15;                 // j-within-frag
  const int kd0 = (lane >> 4) * 8;           // d-run base (kc adds 32)

  auto stageV = [&](int buf, int jt) {       // 2 chunks/wave: 2 sub-tiles x 64 d-rows
    const int j0 = jt * 128;
    for (int i = 0; i < 2; ++i) {
      int c = wid*2 + i;                     // 0..15
      int sub = c >> 3, dr = (c & 7)*8 + lrow;
      gload_lds16(Vthead + (size_t)dr*SEQ + j0 + sub*64 + swz, &Vs[buf][c*512]);
    }
  };

  // ---- pass A: denominators (barrier-free, K direct from global) ----
  float lsum[4] = {0.f,0.f,0.f,0.f};
  #pragma unroll 2
  for (int jt = 0; jt < 16; ++jt) {
    const int j0 = jt * 64;
    bf16x8 kfr[8];
    #pragma unroll
    for (int kc = 0; kc < 2; ++kc)
      #pragma unroll
      for (int jf = 0; jf < 4; ++jf)
        kfr[kc*4+jf] = *(const bf16x8*)(Khead + (size_t)(j0 + jf*16 + kjl)*HD + kd0 + kc*32);
    f32x4 sac[4] = {zero4, zero4, zero4, zero4};
    __builtin_amdgcn_s_setprio(1);
    #pragma unroll
    for (int kc = 0; kc < 2; ++kc)
      #pragma unroll
      for (int jf = 0; jf < 4; ++jf)
        sac[jf] = __builtin_amdgcn_mfma_f32_16x16x32_bf16(qf[kc], kfr[kc*4+jf], sac[jf], 0, 0, 0);
    __builtin_amdgcn_s_setprio(0);
    #pragma unroll
    for (int jf = 0; jf < 4; ++jf)
      #pragma unroll
      for (int r = 0; r < 4; ++r)
        lsum[r] += __expf(sac[jf][r] * SCALE_F);
  }
  for (int m = 1; m < 16; m <<= 1)
    for (int r = 0; r < 4; ++r)
      lsum[r] += __shfl_xor(lsum[r], m, 64);
  float linv[4];
  for (int r = 0; r < 4; ++r) linv[r] = 1.0f / lsum[r];

  // ---- pass B ----
  f32x4 cacc[4] = {zero4, zero4, zero4, zero4};
  short* Wsw = &Ws[wid][0];
  float* awbase = attn_out + (size_t)((size_t)h*SEQ + i0 + wid*16)*SEQ;
  stageV(0, 0);
  asm volatile("s_waitcnt vmcnt(0)" ::: "memory");
  __syncthreads();
  int cur = 0;
  for (int jt = 0; jt < 8; ++jt) {
    if (jt < 7) stageV(cur ^ 1, jt + 1);     // 2 lds-loads (oldest VMEM)
    const int j0 = jt * 128;
    #pragma unroll
    for (int half = 0; half < 2; ++half) {
      const short* Vtt = &Vs[cur][half*4096];
      bf16x8 kfr[8];
      #pragma unroll
      for (int kc = 0; kc < 2; ++kc)
        #pragma unroll
        for (int jf = 0; jf < 4; ++jf)
          kfr[kc*4+jf] = *(const bf16x8*)(Khead + (size_t)(j0 + half*64 + jf*16 + kjl)*HD + kd0 + kc*32);
      f32x4 sac[4] = {zero4, zero4, zero4, zero4};
      __builtin_amdgcn_s_setprio(1);
      #pragma unroll
      for (int kc = 0; kc < 2; ++kc)
        #pragma unroll
        for (int jf = 0; jf < 4; ++jf)
          sac[jf] = __builtin_amdgcn_mfma_f32_16x16x32_bf16(qf[kc], kfr[kc*4+jf], sac[jf], 0, 0, 0);
      __builtin_amdgcn_s_setprio(0);
      // normalized bf16 P -> Ws (PV operand AND attn_out source)
      #pragma unroll
      for (int jf = 0; jf < 4; ++jf)
        #pragma unroll
        for (int r = 0; r < 4; ++r) {
          float w = __expf(sac[jf][r] * SCALE_F) * linv[r];
          int row = (lane>>4)*4 + r;
          int col = jf*16 + (lane & 15);
          Wsw[row*64 + (((col>>3) ^ (row & 7))<<3) + (col & 7)] = (short)f2bf(w);
        }
      asm volatile("s_waitcnt lgkmcnt(0)" ::: "memory");  // Ws visible; pins order
      __builtin_amdgcn_s_setprio(1);
      #pragma unroll
      for (int kc = 0; kc < 2; ++kc) {
        bf16x8 wa = frag_ld(Wsw, lane & 15, (lane>>4) + kc*4);
        #pragma unroll
        for (int df = 0; df < 4; ++df) {
          bf16x8 vb = frag_ld(Vtt, df*16 + (lane & 15), (lane>>4) + kc*4);
          cacc[df] = __builtin_amdgcn_mfma_f32_16x16x32_bf16(wa, vb, cacc[df], 0, 0, 0);
        }
      }
      __builtin_amdgcn_s_setprio(0);
      // attn_out: 4x f32x4 non-temporal, 256B contiguous per 16-lane group
      #pragma unroll
      for (int s = 0; s < 4; ++s) {
        int row = (lane>>4) + s*4;
        int lu  = (lane & 15) >> 1;
        uint2 pv = *(const uint2*)(Wsw + row*64 + ((lu ^ (row & 7)) << 3) + (lane & 1)*4);
        f32x4 o;
        o[0] = bf2f((unsigned short)(pv.x & 0xffff));
        o[1] = bf2f((unsigned short)(pv.x >> 16));
        o[2] = bf2f((unsigned short)(pv.y & 0xffff));
        o[3] = bf2f((unsigned short)(pv.y >> 16));
        __builtin_nontemporal_store(o,
            (f32x4*)(awbase + (size_t)row*SEQ + j0 + half*64 + (lane & 15)*4));
      }
    }
    if (jt < 7) {
      // V-lds loads retire before compiler's K-frag waits (in-order); stores
      // may remain in flight: vmcnt(8) never blocks on them.
      asm volatile("s_waitcnt vmcnt(8) lgkmcnt(0)" ::: "memory");
      __builtin_amdgcn_s_barrier();
      cur ^= 1;
    }
  }
  for (int df = 0; df < 4; ++df)
    for (int r = 0; r < 4; ++r) {
      int irow = i0 + wid*16 + (lane>>4)*4 + r;
      ((unsigned short*)ctx)[(size_t)(b*SEQ + irow)*WIDTH + nh*HD + df*16 + (lane & 15)]
          = f2bf(cacc[df][r]);
    }
}

// ---------------- launcher ----------------
extern "C" void kernel_launch(void* const* d_in, const int* in_sizes, int n_in,
                              void* d_out, int out_size, void* d_ws, size_t ws_size,
                              hipStream_t stream) {
  const float* q  = (const float*)d_in[0];
  const float* k  = (const float*)d_in[1];
  const float* v  = (const float*)d_in[2];
  const float* wq = (const float*)d_in[3];
  const float* wk = (const float*)d_in[4];
  const float* wv = (const float*)d_in[5];
  const float* wo = (const float*)d_in[6];

  bf16* wsb = (bf16*)d_ws;
  bf16* qb  = wsb;
  bf16* kb  = qb + 4194304;
  bf16* vb  = kb + 4194304;
  bf16* wqb = vb + 4194304;
  bf16* wkb = wqb + 262144;
  bf16* wvb = wkb + 262144;
  bf16* wob = wvb + 262144;
  bf16* Qh  = wob + 262144;
  bf16* Kh  = Qh + 4194304;
  bf16* Vh  = Kh + 4194304;
  bf16* Vt  = Vh + 4194304;
  bf16* ctx = Vt + 4194304;

  float* x_out    = (float*)d_out;             // (8,1024,512)
  float* attn_out = (float*)d_out + 4194304;   // (8,8,1024,1024)

  cast_all_kernel<<<13312, 256, 0, stream>>>(q, k, v, wq, wk, wv, wo, wsb);
  gemm_qkv<<<768, 256, 0, stream>>>(qb, kb, vb, wqb, wkb, wvb, Qh, Kh, Vh);
  transpose_v<<<1024, 256, 0, stream>>>(Vh, Vt);
  attn_kernel<<<512, 512, 0, stream>>>(Qh, Kh, Vt, attn_out, ctx);
  gemm_out<<<512, 256, 0, stream>>>(ctx, wob, x_out);
}

// Round 16
// 124.116 us; speedup vs baseline: 1.4916x; 1.4916x over previous
//
#include <hip/hip_runtime.h>
#include <hip/hip_bf16.h>

// Fused MHA forward (B=8, I=J=1024, WIDTH=512, NH=8, HD=64), fp32 in/out.
// R16 = R14 (best, 129.3us) + fp32->bf16 cast FUSED into the QKV GEMM:
// A staged as fp32 via async global_load_lds (BK=32, 48KB LDS, 3 blocks/CU),
// converted to bf16 at frag-load with v_cvt_pk_bf16_f32 (RNE == f2bf).
// The 72MB q/k/v cast pass is eliminated. R15's direct-global K reverted
// (fragment gathers from global are issue-bound -- R8 lesson repeated).

typedef __hip_bfloat16 bf16;
typedef __attribute__((ext_vector_type(8))) short bf16x8;   // MFMA A/B frag (4 VGPR)
typedef __attribute__((ext_vector_type(4))) float f32x4;    // MFMA C/D frag, nt-store vec

#define BATCH 8
#define SEQ   1024
#define WIDTH 512
#define NHEAD 8
#define HD    64
#define SCALE_F 0.044194173824159216f     // 512^-0.5 (width, per reference!)

static __device__ __forceinline__ unsigned short f2bf(float x) {
  union { float f; unsigned u; } a; a.f = x;
  unsigned r = a.u + 0x7fffu + ((a.u >> 16) & 1u);   // RNE
  return (unsigned short)(r >> 16);
}
static __device__ __forceinline__ float bf2f(unsigned short u) {
  union { unsigned u; float f; } a; a.u = ((unsigned)u) << 16; return a.f;
}

static __device__ __forceinline__ void gload_lds16(const void* g, void* l) {
  __builtin_amdgcn_global_load_lds((const __attribute__((address_space(1))) void*)g,
                                   (__attribute__((address_space(3))) void*)l,
                                   16, 0, 0);
}

// Swizzled LDS tile: rows of 64 bf16 (128B); 16B-unit phys col = logical ^ (row&7).
static __device__ __forceinline__ bf16x8 frag_ld(const short* tile, int row, int c16) {
  int p = c16 ^ (row & 7);
  return *(const bf16x8*)(tile + row*64 + p*8);
}

// pack 2 fp32 -> 2 bf16 (RNE), low word = a, high word = b
static __device__ __forceinline__ unsigned cvtpk(float a, float b) {
  unsigned d;
  asm("v_cvt_pk_bf16_f32 %0, %1, %2" : "=v"(d) : "v"(a), "v"(b));
  return d;
}

// ---------------- cast fp32 -> bf16 (4 weights only, 4MB) ----------------
__global__ void wcast_kernel(const float* __restrict__ wq, const float* __restrict__ wk,
                             const float* __restrict__ wv, const float* __restrict__ wo,
                             bf16* __restrict__ wsb) {
  const long NW = 65536;     // float4 groups per weight (512*512/4)
  long g = (long)blockIdx.x * blockDim.x + threadIdx.x;
  int t = (int)(g / NW); long o = g - (long)t*NW;
  const float* src = (t==0) ? wq : ((t==1) ? wk : ((t==2) ? wv : wo));
  bf16* dst = wsb + (size_t)t * 262144;
  float4 f = ((const float4*)src)[o];
  ushort4 r4;
  r4.x = f2bf(f.x); r4.y = f2bf(f.y); r4.z = f2bf(f.z); r4.w = f2bf(f.w);
  ((ushort4*)dst)[o] = r4;
}

// ---------------- QKV GEMM with fused cast: C = A_f32 @ W_bf16^T ----------------
// 128x128 tile, BK=32, 16 K-steps, 4 waves. A staged fp32 via global_load_lds
// (16KB/buf, 16B-unit XOR row&7); B staged bf16 (8KB/buf, XOR row&3).
// A frags converted fp32->bf16 with v_cvt_pk_bf16_f32 at load.
__global__ __launch_bounds__(256) void gemm_qkv(const float* __restrict__ Aq,
                                                const float* __restrict__ Ak,
                                                const float* __restrict__ Av,
                                                const bf16* __restrict__ Wb,
                                                bf16* __restrict__ Qh,
                                                bf16* __restrict__ Kh,
                                                bf16* __restrict__ Vh) {
  __shared__ float Af[2][128*32];
  __shared__ short Bs[2][128*32];

  const int bid = blockIdx.x;               // 768 blocks
  const int xcd = bid & 7;
  const int idx = bid >> 3;                 // 0..95
  const int g   = xcd*24 + (idx >> 2);      // 0..191
  const int y   = idx & 3;
  const int z   = g >> 6;                   // 0:q 1:k 2:v
  const int m   = g & 63;

  const float* A = (z==0) ? Aq : ((z==1) ? Ak : Av);
  const bf16* Bw = Wb + (size_t)z * 262144;
  bf16* Cout     = (z==0) ? Qh : ((z==1) ? Kh : Vh);

  const int lane = threadIdx.x & 63;
  const int wid  = threadIdx.x >> 6;
  const int m0 = m * 128;
  const int n0 = y * 128;
  const int wm = (wid >> 1) * 64;
  const int wn = (wid & 1) * 64;

  // A staging decode: chunk c = 8 rows x 8 units(16B); per wave 4 chunks
  const int lrowA = lane >> 3;              // 0..7
  const int luA   = lane & 7;
  // B staging decode: chunk c = 16 rows x 4 units; per wave 2 chunks
  const int lrowB = lane >> 2;              // 0..15
  const int luB   = lane & 3;

  const f32x4 zero4 = {0.f,0.f,0.f,0.f};
  f32x4 acc[4][4];
  for (int i=0;i<4;++i) for (int j=0;j<4;++j) acc[i][j] = zero4;

  auto stage = [&](int buf, int t) {
    const int k0 = t * 32;
    for (int i = 0; i < 4; ++i) {           // A: 16 chunks of 1KB
      int c = wid*4 + i;
      int row = c*8 + lrowA;
      gload_lds16(A + (size_t)(m0 + row)*WIDTH + k0 + ((luA ^ lrowA) * 4), &Af[buf][c*256]);
    }
    for (int i = 0; i < 2; ++i) {           // B: 8 chunks of 1KB
      int c = wid*2 + i;
      int row = c*16 + lrowB;
      gload_lds16(Bw + (size_t)(n0 + row)*WIDTH + k0 + ((luB ^ (lrowB & 3)) * 8), &Bs[buf][c*512]);
    }
  };

  stage(0, 0);
  asm volatile("s_waitcnt vmcnt(0)" ::: "memory");
  __syncthreads();
  int cur = 0;

  const int kg = lane >> 4;                 // 0..3 k-group
  for (int t = 0; t < 16; ++t) {
    if (t < 15) stage(cur ^ 1, t + 1);
    bf16x8 af[4], bfr[4];
    #pragma unroll
    for (int mf = 0; mf < 4; ++mf) {
      int row = wm + mf*16 + (lane & 15);
      const float* rp = &Af[cur][row*32];
      f32x4 lo = *(const f32x4*)(rp + (((2*kg)   ^ (row & 7)) * 4));
      f32x4 hi = *(const f32x4*)(rp + (((2*kg+1) ^ (row & 7)) * 4));
      unsigned d0 = cvtpk(lo[0], lo[1]);
      unsigned d1 = cvtpk(lo[2], lo[3]);
      unsigned d2 = cvtpk(hi[0], hi[1]);
      unsigned d3 = cvtpk(hi[2], hi[3]);
      af[mf][0] = (short)(d0 & 0xffff); af[mf][1] = (short)(d0 >> 16);
      af[mf][2] = (short)(d1 & 0xffff); af[mf][3] = (short)(d1 >> 16);
      af[mf][4] = (short)(d2 & 0xffff); af[mf][5] = (short)(d2 >> 16);
      af[mf][6] = (short)(d3 & 0xffff); af[mf][7] = (short)(d3 >> 16);
    }
    #pragma unroll
    for (int nf = 0; nf < 4; ++nf) {
      int row = wn + nf*16 + (lane & 15);
      bfr[nf] = *(const bf16x8*)(&Bs[cur][row*32 + ((kg ^ (row & 3)) * 8)]);
    }
    #pragma unroll
    for (int mf = 0; mf < 4; ++mf)
      #pragma unroll
      for (int nf = 0; nf < 4; ++nf)
        acc[mf][nf] = __builtin_amdgcn_mfma_f32_16x16x32_bf16(af[mf], bfr[nf], acc[mf][nf], 0,0,0);
    if (t < 15) {
      asm volatile("s_waitcnt vmcnt(0)" ::: "memory");
      __syncthreads();
      cur ^= 1;
    }
  }
  for (int mf=0; mf<4; ++mf)
    for (int nf=0; nf<4; ++nf) {
      int col = n0 + wn + nf*16 + (lane & 15);
      for (int r=0; r<4; ++r) {
        int row = m0 + wm + mf*16 + (lane>>4)*4 + r;
        ((unsigned short*)Cout)[(size_t)row*WIDTH + col] = f2bf(acc[mf][nf][r]);
      }
    }
}

// ---------------- output GEMM: x[8192][512] = ctx @ Wo^T, fp32 nt out ----------------
__global__ __launch_bounds__(256) void gemm_out(const bf16* __restrict__ A,
                                                const bf16* __restrict__ Bw,
                                                float* __restrict__ Cout) {
  __shared__ short As[2][128*64];
  __shared__ short Bs[2][64*64];

  const int bid = blockIdx.x;                // 512 blocks
  const int xcd = bid & 7;
  const int idx = bid >> 3;                  // 0..63
  const int m   = xcd*8 + (idx >> 3);        // 0..63
  const int y   = idx & 7;                   // 0..7 (64-col panels)

  const int lane = threadIdx.x & 63;
  const int wid  = threadIdx.x >> 6;
  const int m0 = m * 128;
  const int n0 = y * 64;
  const int wm = (wid >> 1) * 64;
  const int wn = (wid & 1) * 32;
  const int lrow = lane >> 3;
  const int swz  = ((lane & 7) ^ lrow) * 8;

  const f32x4 zero4 = {0.f,0.f,0.f,0.f};
  f32x4 acc[4][2];
  for (int i=0;i<4;++i) for (int j=0;j<2;++j) acc[i][j] = zero4;

  auto stage = [&](int buf, int t) {
    const int k0 = t * 64;
    for (int i = 0; i < 4; ++i) {
      int c = wid*4 + i;
      int row = c*8 + lrow;
      gload_lds16(A + (size_t)(m0 + row)*WIDTH + k0 + swz, &As[buf][c*512]);
    }
    for (int i = 0; i < 2; ++i) {
      int c = wid*2 + i;
      int row = c*8 + lrow;
      gload_lds16(Bw + (size_t)(n0 + row)*WIDTH + k0 + swz, &Bs[buf][c*512]);
    }
  };

  stage(0, 0);
  asm volatile("s_waitcnt vmcnt(0)" ::: "memory");
  __syncthreads();
  int cur = 0;

  for (int t = 0; t < 8; ++t) {
    if (t < 7) stage(cur ^ 1, t + 1);
    for (int kc = 0; kc < 2; ++kc) {
      bf16x8 af[4], bfr[2];
      for (int mf=0; mf<4; ++mf) af[mf]  = frag_ld(&As[cur][0], wm + mf*16 + (lane&15), (lane>>4) + kc*4);
      for (int nf=0; nf<2; ++nf) bfr[nf] = frag_ld(&Bs[cur][0], wn + nf*16 + (lane&15), (lane>>4) + kc*4);
      for (int mf=0; mf<4; ++mf)
        for (int nf=0; nf<2; ++nf)
          acc[mf][nf] = __builtin_amdgcn_mfma_f32_16x16x32_bf16(af[mf], bfr[nf], acc[mf][nf], 0,0,0);
    }
    if (t < 7) {
      asm volatile("s_waitcnt vmcnt(0)" ::: "memory");
      __syncthreads();
      cur ^= 1;
    }
  }
  for (int mf=0; mf<4; ++mf)
    for (int nf=0; nf<2; ++nf) {
      int col = n0 + wn + nf*16 + (lane & 15);
      for (int r=0; r<4; ++r) {
        int row = m0 + wm + mf*16 + (lane>>4)*4 + r;
        __builtin_nontemporal_store(acc[mf][nf][r], Cout + (size_t)row*WIDTH + col);
      }
    }
}

// ---------------- V transpose: per head (1024,64) -> (64,1024) ----------------
__global__ __launch_bounds__(256) void transpose_v(const bf16* __restrict__ Vh,
                                                   bf16* __restrict__ Vt) {
  __shared__ short t[64][72];
  int h  = blockIdx.x >> 4;
  int j0 = (blockIdx.x & 15) * 64;
  const bf16* src = Vh + (size_t)h * (SEQ*HD);
  bf16* dst = Vt + (size_t)h * (SEQ*HD);
  int tid = threadIdx.x;
  int r  = tid >> 2;
  int c0 = (tid & 3) * 16;
  bf16x8 v0 = *(const bf16x8*)(src + (size_t)(j0 + r)*HD + c0);
  bf16x8 v1 = *(const bf16x8*)(src + (size_t)(j0 + r)*HD + c0 + 8);
  for (int i = 0; i < 8; ++i) { t[r][c0+i] = v0[i]; t[r][c0+8+i] = v1[i]; }
  __syncthreads();
  bf16x8 w0, w1;
  for (int i = 0; i < 8; ++i) { w0[i] = t[c0+i][r]; w1[i] = t[c0+8+i][r]; }
  *(bf16x8*)(dst + (size_t)r*SEQ + j0 + c0)     = w0;
  *(bf16x8*)(dst + (size_t)r*SEQ + j0 + c0 + 8) = w1;
}

// ---------------- fused attention (2-pass, 8-wave, KVBLK=128) ----------------
// Block = 8 waves x 16 rows = 128 q-rows of one head; XCD-chunked (8 heads/XCD).
// Each jt covers 128 K/V columns as two 64-col sub-rounds sharing Ws; 8
// barriers per pass. Exact counted vmcnt(8) at the barrier. (R14 verbatim.)
__global__ __launch_bounds__(512) void attn_kernel(const bf16* __restrict__ Qh,
                                                   const bf16* __restrict__ Kh,
                                                   const bf16* __restrict__ Vt,
                                                   float* __restrict__ attn_out,
                                                   bf16* __restrict__ ctx) {
  __shared__ short Ks[2][128*64];    // [j 0..127][d 0..63], 2 sub-tiles of [64][64]
  __shared__ short Vs[2][128*64];    // 2 sub-tiles [d 0..63][j half*64..+63]
  __shared__ short Ws[8][16*64];

  const int lane = threadIdx.x & 63;
  const int wid  = threadIdx.x >> 6;         // 0..7
  const int bid  = blockIdx.x;
  const int xcd  = bid & 7;
  const int idx  = bid >> 3;                 // 0..63
  const int h    = xcd*8 + (idx >> 3);       // 8 heads/XCD
  const int i0   = (idx & 7) * 128;
  const int b  = h >> 3;
  const int nh = h & 7;

  const bf16* Qhead  = Qh + (size_t)h * (SEQ*HD);
  const bf16* Khead  = Kh + (size_t)h * (SEQ*HD);
  const bf16* Vthead = Vt + (size_t)h * (SEQ*HD);

  const int lrow = lane >> 3;
  const int swz  = ((lane & 7) ^ lrow) * 8;

  const int qrow = i0 + wid*16 + (lane & 15);
  bf16x8 qf[2];
  qf[0] = *(const bf16x8*)(Qhead + (size_t)qrow*HD + (lane>>4)*8);
  qf[1] = *(const bf16x8*)(Qhead + (size_t)qrow*HD + 32 + (lane>>4)*8);

  const f32x4 zero4 = {0.f,0.f,0.f,0.f};

  auto stageK = [&](int buf, int jt) {       // 2 chunks/wave: 128 j-rows
    const int j0 = jt * 128;
    for (int i = 0; i < 2; ++i) {
      int c = wid*2 + i;                     // 0..15
      gload_lds16(Khead + (size_t)(j0 + c*8 + lrow)*HD + swz, &Ks[buf][c*512]);
    }
  };
  auto stageV = [&](int buf, int jt) {       // 2 chunks/wave: 2 sub-tiles x 64 d-rows
    const int j0 = jt * 128;
    for (int i = 0; i < 2; ++i) {
      int c = wid*2 + i;                     // 0..15
      int sub = c >> 3, dr = (c & 7)*8 + lrow;
      gload_lds16(Vthead + (size_t)dr*SEQ + j0 + sub*64 + swz, &Vs[buf][c*512]);
    }
  };

  // ---- pass A: denominators ----
  float lsum[4] = {0.f,0.f,0.f,0.f};
  stageK(0, 0);
  asm volatile("s_waitcnt vmcnt(0)" ::: "memory");
  __syncthreads();
  int cur = 0;
  for (int jt = 0; jt < 8; ++jt) {
    if (jt < 7) stageK(cur ^ 1, jt + 1);
    #pragma unroll
    for (int half = 0; half < 2; ++half) {
      const short* Kt = &Ks[cur][half*4096];
      f32x4 sac[4] = {zero4, zero4, zero4, zero4};
      __builtin_amdgcn_s_setprio(1);
      for (int kc = 0; kc < 2; ++kc)
        for (int jf = 0; jf < 4; ++jf) {
          bf16x8 kf = frag_ld(Kt, jf*16 + (lane & 15), (lane>>4) + kc*4);
          sac[jf] = __builtin_amdgcn_mfma_f32_16x16x32_bf16(qf[kc], kf, sac[jf], 0, 0, 0);
        }
      __builtin_amdgcn_s_setprio(0);
      for (int jf = 0; jf < 4; ++jf)
        for (int r = 0; r < 4; ++r)
          lsum[r] += __expf(sac[jf][r] * SCALE_F);
    }
    if (jt < 7) {
      asm volatile("s_waitcnt vmcnt(0)" ::: "memory");
      __syncthreads();
      cur ^= 1;
    }
  }
  for (int m = 1; m < 16; m <<= 1)
    for (int r = 0; r < 4; ++r)
      lsum[r] += __shfl_xor(lsum[r], m, 64);
  float linv[4];
  for (int r = 0; r < 4; ++r) linv[r] = 1.0f / lsum[r];
  __syncthreads();

  // ---- pass B ----
  f32x4 cacc[4] = {zero4, zero4, zero4, zero4};
  short* Wsw = &Ws[wid][0];
  float* awbase = attn_out + (size_t)((size_t)h*SEQ + i0 + wid*16)*SEQ;
  stageK(0, 0); stageV(0, 0);
  asm volatile("s_waitcnt vmcnt(0)" ::: "memory");
  __syncthreads();
  cur = 0;
  for (int jt = 0; jt < 8; ++jt) {
    if (jt < 7) { stageK(cur ^ 1, jt + 1); stageV(cur ^ 1, jt + 1); }  // 4 loads, oldest
    const int j0 = jt * 128;
    #pragma unroll
    for (int half = 0; half < 2; ++half) {
      const short* Kt  = &Ks[cur][half*4096];
      const short* Vtt = &Vs[cur][half*4096];
      f32x4 sac[4] = {zero4, zero4, zero4, zero4};
      __builtin_amdgcn_s_setprio(1);
      for (int kc = 0; kc < 2; ++kc)
        for (int jf = 0; jf < 4; ++jf) {
          bf16x8 kf = frag_ld(Kt, jf*16 + (lane & 15), (lane>>4) + kc*4);
          sac[jf] = __builtin_amdgcn_mfma_f32_16x16x32_bf16(qf[kc], kf, sac[jf], 0, 0, 0);
        }
      __builtin_amdgcn_s_setprio(0);
      // normalized bf16 P -> Ws (PV operand AND attn_out source)
      for (int jf = 0; jf < 4; ++jf)
        for (int r = 0; r < 4; ++r) {
          float w = __expf(sac[jf][r] * SCALE_F) * linv[r];
          int row = (lane>>4)*4 + r;
          int col = jf*16 + (lane & 15);
          Wsw[row*64 + (((col>>3) ^ (row & 7))<<3) + (col & 7)] = (short)f2bf(w);
        }
      asm volatile("s_waitcnt lgkmcnt(0)" ::: "memory");  // Ws visible; pins load<store order
      __builtin_amdgcn_s_setprio(1);
      for (int kc = 0; kc < 2; ++kc) {
        bf16x8 wa = frag_ld(Wsw, lane & 15, (lane>>4) + kc*4);
        for (int df = 0; df < 4; ++df) {
          bf16x8 vb = frag_ld(Vtt, df*16 + (lane & 15), (lane>>4) + kc*4);
          cacc[df] = __builtin_amdgcn_mfma_f32_16x16x32_bf16(wa, vb, cacc[df], 0, 0, 0);
        }
      }
      __builtin_amdgcn_s_setprio(0);
      // attn_out: 4x f32x4 non-temporal, 256B contiguous per 16-lane group
      #pragma unroll
      for (int s = 0; s < 4; ++s) {
        int row = (lane>>4) + s*4;
        int lu  = (lane & 15) >> 1;
        uint2 pv = *(const uint2*)(Wsw + row*64 + ((lu ^ (row & 7)) << 3) + (lane & 1)*4);
        f32x4 o;
        o[0] = bf2f((unsigned short)(pv.x & 0xffff));
        o[1] = bf2f((unsigned short)(pv.x >> 16));
        o[2] = bf2f((unsigned short)(pv.y & 0xffff));
        o[3] = bf2f((unsigned short)(pv.y >> 16));
        __builtin_nontemporal_store(o,
            (f32x4*)(awbase + (size_t)row*SEQ + j0 + half*64 + (lane & 15)*4));
      }
    }
    if (jt < 7) {
      asm volatile("s_waitcnt vmcnt(8) lgkmcnt(0)" ::: "memory");
      __builtin_amdgcn_s_barrier();
      cur ^= 1;
    }
  }
  for (int df = 0; df < 4; ++df)
    for (int r = 0; r < 4; ++r) {
      int irow = i0 + wid*16 + (lane>>4)*4 + r;
      ((unsigned short*)ctx)[(size_t)(b*SEQ + irow)*WIDTH + nh*HD + df*16 + (lane & 15)]
          = f2bf(cacc[df][r]);
    }
}

// ---------------- launcher ----------------
extern "C" void kernel_launch(void* const* d_in, const int* in_sizes, int n_in,
                              void* d_out, int out_size, void* d_ws, size_t ws_size,
                              hipStream_t stream) {
  const float* q  = (const float*)d_in[0];
  const float* k  = (const float*)d_in[1];
  const float* v  = (const float*)d_in[2];
  const float* wq = (const float*)d_in[3];
  const float* wk = (const float*)d_in[4];
  const float* wv = (const float*)d_in[5];
  const float* wo = (const float*)d_in[6];

  bf16* wsb = (bf16*)d_ws;
  bf16* wqb = wsb;                      // 4 x 262144 (wq,wk,wv,wo)
  bf16* wob = wqb + 3*262144;
  bf16* Qh  = wqb + 4*262144;
  bf16* Kh  = Qh + 4194304;
  bf16* Vh  = Kh + 4194304;
  bf16* Vt  = Vh + 4194304;
  bf16* ctx = Vt + 4194304;

  float* x_out    = (float*)d_out;             // (8,1024,512)
  float* attn_out = (float*)d_out + 4194304;   // (8,8,1024,1024)

  wcast_kernel<<<1024, 256, 0, stream>>>(wq, wk, wv, wo, wqb);
  gemm_qkv<<<768, 256, 0, stream>>>(q, k, v, wqb, Qh, Kh, Vh);
  transpose_v<<<1024, 256, 0, stream>>>(Vh, Vt);
  attn_kernel<<<512, 512, 0, stream>>>(Qh, Kh, Vt, attn_out, ctx);
  gemm_out<<<512, 256, 0, stream>>>(ctx, wob, x_out);
}

// Round 17
// 122.178 us; speedup vs baseline: 1.5153x; 1.0159x over previous
//
#include <hip/hip_runtime.h>
#include <hip/hip_bf16.h>

// Fused MHA forward (B=8, I=J=1024, WIDTH=512, NH=8, HD=64), fp32 in/out.
// R17 = R16 + ONE change in attn: SWAPPED QK^T (mfma(kf,qf) -- same frags,
// transposed output). Each lane then owns 4 consecutive j per frag for its
// column i=lane&15: P-writes become 4x ds_write_b64 (was 16x ds_write_u16),
// lsum becomes one scalar + 2 shuffles (was 4 + 4). Everything else R16.

typedef __hip_bfloat16 bf16;
typedef __attribute__((ext_vector_type(8))) short bf16x8;   // MFMA A/B frag (4 VGPR)
typedef __attribute__((ext_vector_type(4))) float f32x4;    // MFMA C/D frag, nt-store vec

#define BATCH 8
#define SEQ   1024
#define WIDTH 512
#define NHEAD 8
#define HD    64
#define SCALE_F 0.044194173824159216f     // 512^-0.5 (width, per reference!)

static __device__ __forceinline__ unsigned short f2bf(float x) {
  union { float f; unsigned u; } a; a.f = x;
  unsigned r = a.u + 0x7fffu + ((a.u >> 16) & 1u);   // RNE
  return (unsigned short)(r >> 16);
}
static __device__ __forceinline__ float bf2f(unsigned short u) {
  union { unsigned u; float f; } a; a.u = ((unsigned)u) << 16; return a.f;
}

static __device__ __forceinline__ void gload_lds16(const void* g, void* l) {
  __builtin_amdgcn_global_load_lds((const __attribute__((address_space(1))) void*)g,
                                   (__attribute__((address_space(3))) void*)l,
                                   16, 0, 0);
}

// Swizzled LDS tile: rows of 64 bf16 (128B); 16B-unit phys col = logical ^ (row&7).
static __device__ __forceinline__ bf16x8 frag_ld(const short* tile, int row, int c16) {
  int p = c16 ^ (row & 7);
  return *(const bf16x8*)(tile + row*64 + p*8);
}

// pack 2 fp32 -> 2 bf16 (RNE), low word = a, high word = b
static __device__ __forceinline__ unsigned cvtpk(float a, float b) {
  unsigned d;
  asm("v_cvt_pk_bf16_f32 %0, %1, %2" : "=v"(d) : "v"(a), "v"(b));
  return d;
}

// ---------------- cast fp32 -> bf16 (4 weights only, 4MB) ----------------
__global__ void wcast_kernel(const float* __restrict__ wq, const float* __restrict__ wk,
                             const float* __restrict__ wv, const float* __restrict__ wo,
                             bf16* __restrict__ wsb) {
  const long NW = 65536;     // float4 groups per weight (512*512/4)
  long g = (long)blockIdx.x * blockDim.x + threadIdx.x;
  int t = (int)(g / NW); long o = g - (long)t*NW;
  const float* src = (t==0) ? wq : ((t==1) ? wk : ((t==2) ? wv : wo));
  bf16* dst = wsb + (size_t)t * 262144;
  float4 f = ((const float4*)src)[o];
  ushort4 r4;
  r4.x = f2bf(f.x); r4.y = f2bf(f.y); r4.z = f2bf(f.z); r4.w = f2bf(f.w);
  ((ushort4*)dst)[o] = r4;
}

// ---------------- QKV GEMM with fused cast: C = A_f32 @ W_bf16^T ----------------
// 128x128 tile, BK=32, 16 K-steps, 4 waves. A staged fp32 via global_load_lds
// (16KB/buf, 16B-unit XOR row&7); B staged bf16 (8KB/buf, XOR row&3).
// A frags converted fp32->bf16 with v_cvt_pk_bf16_f32 at load.
__global__ __launch_bounds__(256) void gemm_qkv(const float* __restrict__ Aq,
                                                const float* __restrict__ Ak,
                                                const float* __restrict__ Av,
                                                const bf16* __restrict__ Wb,
                                                bf16* __restrict__ Qh,
                                                bf16* __restrict__ Kh,
                                                bf16* __restrict__ Vh) {
  __shared__ float Af[2][128*32];
  __shared__ short Bs[2][128*32];

  const int bid = blockIdx.x;               // 768 blocks
  const int xcd = bid & 7;
  const int idx = bid >> 3;                 // 0..95
  const int g   = xcd*24 + (idx >> 2);      // 0..191
  const int y   = idx & 3;
  const int z   = g >> 6;                   // 0:q 1:k 2:v
  const int m   = g & 63;

  const float* A = (z==0) ? Aq : ((z==1) ? Ak : Av);
  const bf16* Bw = Wb + (size_t)z * 262144;
  bf16* Cout     = (z==0) ? Qh : ((z==1) ? Kh : Vh);

  const int lane = threadIdx.x & 63;
  const int wid  = threadIdx.x >> 6;
  const int m0 = m * 128;
  const int n0 = y * 128;
  const int wm = (wid >> 1) * 64;
  const int wn = (wid & 1) * 64;

  const int lrowA = lane >> 3;              // 0..7
  const int luA   = lane & 7;
  const int lrowB = lane >> 2;              // 0..15
  const int luB   = lane & 3;

  const f32x4 zero4 = {0.f,0.f,0.f,0.f};
  f32x4 acc[4][4];
  for (int i=0;i<4;++i) for (int j=0;j<4;++j) acc[i][j] = zero4;

  auto stage = [&](int buf, int t) {
    const int k0 = t * 32;
    for (int i = 0; i < 4; ++i) {           // A: 16 chunks of 1KB
      int c = wid*4 + i;
      int row = c*8 + lrowA;
      gload_lds16(A + (size_t)(m0 + row)*WIDTH + k0 + ((luA ^ lrowA) * 4), &Af[buf][c*256]);
    }
    for (int i = 0; i < 2; ++i) {           // B: 8 chunks of 1KB
      int c = wid*2 + i;
      int row = c*16 + lrowB;
      gload_lds16(Bw + (size_t)(n0 + row)*WIDTH + k0 + ((luB ^ (lrowB & 3)) * 8), &Bs[buf][c*512]);
    }
  };

  stage(0, 0);
  asm volatile("s_waitcnt vmcnt(0)" ::: "memory");
  __syncthreads();
  int cur = 0;

  const int kg = lane >> 4;                 // 0..3 k-group
  for (int t = 0; t < 16; ++t) {
    if (t < 15) stage(cur ^ 1, t + 1);
    bf16x8 af[4], bfr[4];
    #pragma unroll
    for (int mf = 0; mf < 4; ++mf) {
      int row = wm + mf*16 + (lane & 15);
      const float* rp = &Af[cur][row*32];
      f32x4 lo = *(const f32x4*)(rp + (((2*kg)   ^ (row & 7)) * 4));
      f32x4 hi = *(const f32x4*)(rp + (((2*kg+1) ^ (row & 7)) * 4));
      unsigned d0 = cvtpk(lo[0], lo[1]);
      unsigned d1 = cvtpk(lo[2], lo[3]);
      unsigned d2 = cvtpk(hi[0], hi[1]);
      unsigned d3 = cvtpk(hi[2], hi[3]);
      af[mf][0] = (short)(d0 & 0xffff); af[mf][1] = (short)(d0 >> 16);
      af[mf][2] = (short)(d1 & 0xffff); af[mf][3] = (short)(d1 >> 16);
      af[mf][4] = (short)(d2 & 0xffff); af[mf][5] = (short)(d2 >> 16);
      af[mf][6] = (short)(d3 & 0xffff); af[mf][7] = (short)(d3 >> 16);
    }
    #pragma unroll
    for (int nf = 0; nf < 4; ++nf) {
      int row = wn + nf*16 + (lane & 15);
      bfr[nf] = *(const bf16x8*)(&Bs[cur][row*32 + ((kg ^ (row & 3)) * 8)]);
    }
    #pragma unroll
    for (int mf = 0; mf < 4; ++mf)
      #pragma unroll
      for (int nf = 0; nf < 4; ++nf)
        acc[mf][nf] = __builtin_amdgcn_mfma_f32_16x16x32_bf16(af[mf], bfr[nf], acc[mf][nf], 0,0,0);
    if (t < 15) {
      asm volatile("s_waitcnt vmcnt(0)" ::: "memory");
      __syncthreads();
      cur ^= 1;
    }
  }
  for (int mf=0; mf<4; ++mf)
    for (int nf=0; nf<4; ++nf) {
      int col = n0 + wn + nf*16 + (lane & 15);
      for (int r=0; r<4; ++r) {
        int row = m0 + wm + mf*16 + (lane>>4)*4 + r;
        ((unsigned short*)Cout)[(size_t)row*WIDTH + col] = f2bf(acc[mf][nf][r]);
      }
    }
}

// ---------------- output GEMM: x[8192][512] = ctx @ Wo^T, fp32 nt out ----------------
__global__ __launch_bounds__(256) void gemm_out(const bf16* __restrict__ A,
                                                const bf16* __restrict__ Bw,
                                                float* __restrict__ Cout) {
  __shared__ short As[2][128*64];
  __shared__ short Bs[2][64*64];

  const int bid = blockIdx.x;                // 512 blocks
  const int xcd = bid & 7;
  const int idx = bid >> 3;                  // 0..63
  const int m   = xcd*8 + (idx >> 3);        // 0..63
  const int y   = idx & 7;                   // 0..7 (64-col panels)

  const int lane = threadIdx.x & 63;
  const int wid  = threadIdx.x >> 6;
  const int m0 = m * 128;
  const int n0 = y * 64;
  const int wm = (wid >> 1) * 64;
  const int wn = (wid & 1) * 32;
  const int lrow = lane >> 3;
  const int swz  = ((lane & 7) ^ lrow) * 8;

  const f32x4 zero4 = {0.f,0.f,0.f,0.f};
  f32x4 acc[4][2];
  for (int i=0;i<4;++i) for (int j=0;j<2;++j) acc[i][j] = zero4;

  auto stage = [&](int buf, int t) {
    const int k0 = t * 64;
    for (int i = 0; i < 4; ++i) {
      int c = wid*4 + i;
      int row = c*8 + lrow;
      gload_lds16(A + (size_t)(m0 + row)*WIDTH + k0 + swz, &As[buf][c*512]);
    }
    for (int i = 0; i < 2; ++i) {
      int c = wid*2 + i;
      int row = c*8 + lrow;
      gload_lds16(Bw + (size_t)(n0 + row)*WIDTH + k0 + swz, &Bs[buf][c*512]);
    }
  };

  stage(0, 0);
  asm volatile("s_waitcnt vmcnt(0)" ::: "memory");
  __syncthreads();
  int cur = 0;

  for (int t = 0; t < 8; ++t) {
    if (t < 7) stage(cur ^ 1, t + 1);
    for (int kc = 0; kc < 2; ++kc) {
      bf16x8 af[4], bfr[2];
      for (int mf=0; mf<4; ++mf) af[mf]  = frag_ld(&As[cur][0], wm + mf*16 + (lane&15), (lane>>4) + kc*4);
      for (int nf=0; nf<2; ++nf) bfr[nf] = frag_ld(&Bs[cur][0], wn + nf*16 + (lane&15), (lane>>4) + kc*4);
      for (int mf=0; mf<4; ++mf)
        for (int nf=0; nf<2; ++nf)
          acc[mf][nf] = __builtin_amdgcn_mfma_f32_16x16x32_bf16(af[mf], bfr[nf], acc[mf][nf], 0,0,0);
    }
    if (t < 7) {
      asm volatile("s_waitcnt vmcnt(0)" ::: "memory");
      __syncthreads();
      cur ^= 1;
    }
  }
  for (int mf=0; mf<4; ++mf)
    for (int nf=0; nf<2; ++nf) {
      int col = n0 + wn + nf*16 + (lane & 15);
      for (int r=0; r<4; ++r) {
        int row = m0 + wm + mf*16 + (lane>>4)*4 + r;
        __builtin_nontemporal_store(acc[mf][nf][r], Cout + (size_t)row*WIDTH + col);
      }
    }
}

// ---------------- V transpose: per head (1024,64) -> (64,1024) ----------------
__global__ __launch_bounds__(256) void transpose_v(const bf16* __restrict__ Vh,
                                                   bf16* __restrict__ Vt) {
  __shared__ short t[64][72];
  int h  = blockIdx.x >> 4;
  int j0 = (blockIdx.x & 15) * 64;
  const bf16* src = Vh + (size_t)h * (SEQ*HD);
  bf16* dst = Vt + (size_t)h * (SEQ*HD);
  int tid = threadIdx.x;
  int r  = tid >> 2;
  int c0 = (tid & 3) * 16;
  bf16x8 v0 = *(const bf16x8*)(src + (size_t)(j0 + r)*HD + c0);
  bf16x8 v1 = *(const bf16x8*)(src + (size_t)(j0 + r)*HD + c0 + 8);
  for (int i = 0; i < 8; ++i) { t[r][c0+i] = v0[i]; t[r][c0+8+i] = v1[i]; }
  __syncthreads();
  bf16x8 w0, w1;
  for (int i = 0; i < 8; ++i) { w0[i] = t[c0+i][r]; w1[i] = t[c0+8+i][r]; }
  *(bf16x8*)(dst + (size_t)r*SEQ + j0 + c0)     = w0;
  *(bf16x8*)(dst + (size_t)r*SEQ + j0 + c0 + 8) = w1;
}

// ---------------- fused attention (2-pass, 8-wave, KVBLK=128, swapped QK^T) ----------------
// Block = 8 waves x 16 rows = 128 q-rows of one head; XCD-chunked (8 heads/XCD).
// Swapped QK^T: sac = mfma(kf, qf) = S^T -- lane owns col i=lane&15, with 4
// CONSECUTIVE j per frag. lsum is a per-lane scalar (2-shuffle reduce);
// P-writes are 4x ds_write_b64 per sub-round. PV/attn_out/ctx unchanged.
__global__ __launch_bounds__(512) void attn_kernel(const bf16* __restrict__ Qh,
                                                   const bf16* __restrict__ Kh,
                                                   const bf16* __restrict__ Vt,
                                                   float* __restrict__ attn_out,
                                                   bf16* __restrict__ ctx) {
  __shared__ short Ks[2][128*64];    // [j 0..127][d 0..63], 2 sub-tiles of [64][64]
  __shared__ short Vs[2][128*64];    // 2 sub-tiles [d 0..63][j half*64..+63]
  __shared__ short Ws[8][16*64];

  const int lane = threadIdx.x & 63;
  const int wid  = threadIdx.x >> 6;         // 0..7
  const int bid  = blockIdx.x;
  const int xcd  = bid & 7;
  const int idx  = bid >> 3;                 // 0..63
  const int h    = xcd*8 + (idx >> 3);       // 8 heads/XCD
  const int i0   = (idx & 7) * 128;
  const int b  = h >> 3;
  const int nh = h & 7;

  const bf16* Qhead  = Qh + (size_t)h * (SEQ*HD);
  const bf16* Khead  = Kh + (size_t)h * (SEQ*HD);
  const bf16* Vthead = Vt + (size_t)h * (SEQ*HD);

  const int lrow = lane >> 3;
  const int swz  = ((lane & 7) ^ lrow) * 8;

  const int qrow = i0 + wid*16 + (lane & 15);
  bf16x8 qf[2];
  qf[0] = *(const bf16x8*)(Qhead + (size_t)qrow*HD + (lane>>4)*8);
  qf[1] = *(const bf16x8*)(Qhead + (size_t)qrow*HD + 32 + (lane>>4)*8);

  const f32x4 zero4 = {0.f,0.f,0.f,0.f};

  auto stageK = [&](int buf, int jt) {       // 2 chunks/wave: 128 j-rows
    const int j0 = jt * 128;
    for (int i = 0; i < 2; ++i) {
      int c = wid*2 + i;                     // 0..15
      gload_lds16(Khead + (size_t)(j0 + c*8 + lrow)*HD + swz, &Ks[buf][c*512]);
    }
  };
  auto stageV = [&](int buf, int jt) {       // 2 chunks/wave: 2 sub-tiles x 64 d-rows
    const int j0 = jt * 128;
    for (int i = 0; i < 2; ++i) {
      int c = wid*2 + i;                     // 0..15
      int sub = c >> 3, dr = (c & 7)*8 + lrow;
      gload_lds16(Vthead + (size_t)dr*SEQ + j0 + sub*64 + swz, &Vs[buf][c*512]);
    }
  };

  // ---- pass A: denominators (swapped: per-lane scalar for i=lane&15) ----
  float lsum = 0.f;
  stageK(0, 0);
  asm volatile("s_waitcnt vmcnt(0)" ::: "memory");
  __syncthreads();
  int cur = 0;
  for (int jt = 0; jt < 8; ++jt) {
    if (jt < 7) stageK(cur ^ 1, jt + 1);
    #pragma unroll
    for (int half = 0; half < 2; ++half) {
      const short* Kt = &Ks[cur][half*4096];
      f32x4 sac[4] = {zero4, zero4, zero4, zero4};
      __builtin_amdgcn_s_setprio(1);
      for (int kc = 0; kc < 2; ++kc)
        for (int jf = 0; jf < 4; ++jf) {
          bf16x8 kf = frag_ld(Kt, jf*16 + (lane & 15), (lane>>4) + kc*4);
          sac[jf] = __builtin_amdgcn_mfma_f32_16x16x32_bf16(kf, qf[kc], sac[jf], 0, 0, 0);
        }
      __builtin_amdgcn_s_setprio(0);
      for (int jf = 0; jf < 4; ++jf)
        for (int r = 0; r < 4; ++r)
          lsum += __expf(sac[jf][r] * SCALE_F);
    }
    if (jt < 7) {
      asm volatile("s_waitcnt vmcnt(0)" ::: "memory");
      __syncthreads();
      cur ^= 1;
    }
  }
  lsum += __shfl_xor(lsum, 16, 64);
  lsum += __shfl_xor(lsum, 32, 64);
  const float linv = 1.0f / lsum;
  __syncthreads();

  // ---- pass B ----
  f32x4 cacc[4] = {zero4, zero4, zero4, zero4};
  short* Wsw = &Ws[wid][0];
  float* awbase = attn_out + (size_t)((size_t)h*SEQ + i0 + wid*16)*SEQ;
  stageK(0, 0); stageV(0, 0);
  asm volatile("s_waitcnt vmcnt(0)" ::: "memory");
  __syncthreads();
  cur = 0;
  const int prow = lane & 15;                       // Ws row (i)
  const int pcb  = (lane >> 4) * 4;                 // col base within 16 (j)
  for (int jt = 0; jt < 8; ++jt) {
    if (jt < 7) { stageK(cur ^ 1, jt + 1); stageV(cur ^ 1, jt + 1); }  // 4 loads, oldest
    const int j0 = jt * 128;
    #pragma unroll
    for (int half = 0; half < 2; ++half) {
      const short* Kt  = &Ks[cur][half*4096];
      const short* Vtt = &Vs[cur][half*4096];
      f32x4 sac[4] = {zero4, zero4, zero4, zero4};
      __builtin_amdgcn_s_setprio(1);
      for (int kc = 0; kc < 2; ++kc)
        for (int jf = 0; jf < 4; ++jf) {
          bf16x8 kf = frag_ld(Kt, jf*16 + (lane & 15), (lane>>4) + kc*4);
          sac[jf] = __builtin_amdgcn_mfma_f32_16x16x32_bf16(kf, qf[kc], sac[jf], 0, 0, 0);
        }
      __builtin_amdgcn_s_setprio(0);
      // normalized bf16 P -> Ws: per frag, 4 consecutive j -> one ds_write_b64
      #pragma unroll
      for (int jf = 0; jf < 4; ++jf) {
        float w0 = __expf(sac[jf][0] * SCALE_F) * linv;
        float w1 = __expf(sac[jf][1] * SCALE_F) * linv;
        float w2 = __expf(sac[jf][2] * SCALE_F) * linv;
        float w3 = __expf(sac[jf][3] * SCALE_F) * linv;
        uint2 pk;
        pk.x = (unsigned)f2bf(w0) | ((unsigned)f2bf(w1) << 16);
        pk.y = (unsigned)f2bf(w2) | ((unsigned)f2bf(w3) << 16);
        int colb = jf*16 + pcb;
        *(uint2*)(&Wsw[prow*64 + (((colb >> 3) ^ (prow & 7)) << 3) + (colb & 7)]) = pk;
      }
      asm volatile("s_waitcnt lgkmcnt(0)" ::: "memory");  // Ws visible; pins load<store order
      __builtin_amdgcn_s_setprio(1);
      for (int kc = 0; kc < 2; ++kc) {
        bf16x8 wa = frag_ld(Wsw, lane & 15, (lane>>4) + kc*4);
        for (int df = 0; df < 4; ++df) {
          bf16x8 vb = frag_ld(Vtt, df*16 + (lane & 15), (lane>>4) + kc*4);
          cacc[df] = __builtin_amdgcn_mfma_f32_16x16x32_bf16(wa, vb, cacc[df], 0, 0, 0);
        }
      }
      __builtin_amdgcn_s_setprio(0);
      // attn_out: 4x f32x4 non-temporal, 256B contiguous per 16-lane group
      #pragma unroll
      for (int s = 0; s < 4; ++s) {
        int row = (lane>>4) + s*4;
        int lu  = (lane & 15) >> 1;
        uint2 pv = *(const uint2*)(Wsw + row*64 + ((lu ^ (row & 7)) << 3) + (lane & 1)*4);
        f32x4 o;
        o[0] = bf2f((unsigned short)(pv.x & 0xffff));
        o[1] = bf2f((unsigned short)(pv.x >> 16));
        o[2] = bf2f((unsigned short)(pv.y & 0xffff));
        o[3] = bf2f((unsigned short)(pv.y >> 16));
        __builtin_nontemporal_store(o,
            (f32x4*)(awbase + (size_t)row*SEQ + j0 + half*64 + (lane & 15)*4));
      }
    }
    if (jt < 7) {
      asm volatile("s_waitcnt vmcnt(8) lgkmcnt(0)" ::: "memory");
      __builtin_amdgcn_s_barrier();
      cur ^= 1;
    }
  }
  for (int df = 0; df < 4; ++df)
    for (int r = 0; r < 4; ++r) {
      int irow = i0 + wid*16 + (lane>>4)*4 + r;
      ((unsigned short*)ctx)[(size_t)(b*SEQ + irow)*WIDTH + nh*HD + df*16 + (lane & 15)]
          = f2bf(cacc[df][r]);
    }
}

// ---------------- launcher ----------------
extern "C" void kernel_launch(void* const* d_in, const int* in_sizes, int n_in,
                              void* d_out, int out_size, void* d_ws, size_t ws_size,
                              hipStream_t stream) {
  const float* q  = (const float*)d_in[0];
  const float* k  = (const float*)d_in[1];
  const float* v  = (const float*)d_in[2];
  const float* wq = (const float*)d_in[3];
  const float* wk = (const float*)d_in[4];
  const float* wv = (const float*)d_in[5];
  const float* wo = (const float*)d_in[6];

  bf16* wsb = (bf16*)d_ws;
  bf16* wqb = wsb;                      // 4 x 262144 (wq,wk,wv,wo)
  bf16* wob = wqb + 3*262144;
  bf16* Qh  = wqb + 4*262144;
  bf16* Kh  = Qh + 4194304;
  bf16* Vh  = Kh + 4194304;
  bf16* Vt  = Vh + 4194304;
  bf16* ctx = Vt + 4194304;

  float* x_out    = (float*)d_out;             // (8,1024,512)
  float* attn_out = (float*)d_out + 4194304;   // (8,8,1024,1024)

  wcast_kernel<<<1024, 256, 0, stream>>>(wq, wk, wv, wo, wqb);
  gemm_qkv<<<768, 256, 0, stream>>>(q, k, v, wqb, Qh, Kh, Vh);
  transpose_v<<<1024, 256, 0, stream>>>(Vh, Vt);
  attn_kernel<<<512, 512, 0, stream>>>(Qh, Kh, Vt, attn_out, ctx);
  gemm_out<<<512, 256, 0, stream>>>(ctx, wob, x_out);
}

// Round 19
// 121.524 us; speedup vs baseline: 1.5234x; 1.0054x over previous
//
#include <hip/hip_runtime.h>
#include <hip/hip_bf16.h>

// Fused MHA forward (B=8, I=J=1024, WIDTH=512, NH=8, HD=64), fp32 in/out.
// R19 = R17 (best, 122.2us; R18's tr-read reverted -- HW layout mismatch) +
// ONE change: attention pass A uses a 4-deep K pipeline (KV[4] ring reusing
// the V buffers that idle during pass A) with counted vmcnt(4/2/0) waits.
// Pass B uses the same KV slots exactly as R17's Ks[cur]/Vs[cur].

typedef __hip_bfloat16 bf16;
typedef __attribute__((ext_vector_type(8))) short bf16x8;   // MFMA A/B frag (4 VGPR)
typedef __attribute__((ext_vector_type(4))) float f32x4;    // MFMA C/D frag, nt-store vec

#define BATCH 8
#define SEQ   1024
#define WIDTH 512
#define NHEAD 8
#define HD    64
#define SCALE_F 0.044194173824159216f     // 512^-0.5 (width, per reference!)

static __device__ __forceinline__ unsigned short f2bf(float x) {
  union { float f; unsigned u; } a; a.f = x;
  unsigned r = a.u + 0x7fffu + ((a.u >> 16) & 1u);   // RNE
  return (unsigned short)(r >> 16);
}
static __device__ __forceinline__ float bf2f(unsigned short u) {
  union { unsigned u; float f; } a; a.u = ((unsigned)u) << 16; return a.f;
}

static __device__ __forceinline__ void gload_lds16(const void* g, void* l) {
  __builtin_amdgcn_global_load_lds((const __attribute__((address_space(1))) void*)g,
                                   (__attribute__((address_space(3))) void*)l,
                                   16, 0, 0);
}

// Swizzled LDS tile: rows of 64 bf16 (128B); 16B-unit phys col = logical ^ (row&7).
static __device__ __forceinline__ bf16x8 frag_ld(const short* tile, int row, int c16) {
  int p = c16 ^ (row & 7);
  return *(const bf16x8*)(tile + row*64 + p*8);
}

// pack 2 fp32 -> 2 bf16 (RNE), low word = a, high word = b
static __device__ __forceinline__ unsigned cvtpk(float a, float b) {
  unsigned d;
  asm("v_cvt_pk_bf16_f32 %0, %1, %2" : "=v"(d) : "v"(a), "v"(b));
  return d;
}

// ---------------- cast fp32 -> bf16 (4 weights only, 4MB) ----------------
__global__ void wcast_kernel(const float* __restrict__ wq, const float* __restrict__ wk,
                             const float* __restrict__ wv, const float* __restrict__ wo,
                             bf16* __restrict__ wsb) {
  const long NW = 65536;     // float4 groups per weight (512*512/4)
  long g = (long)blockIdx.x * blockDim.x + threadIdx.x;
  int t = (int)(g / NW); long o = g - (long)t*NW;
  const float* src = (t==0) ? wq : ((t==1) ? wk : ((t==2) ? wv : wo));
  bf16* dst = wsb + (size_t)t * 262144;
  float4 f = ((const float4*)src)[o];
  ushort4 r4;
  r4.x = f2bf(f.x); r4.y = f2bf(f.y); r4.z = f2bf(f.z); r4.w = f2bf(f.w);
  ((ushort4*)dst)[o] = r4;
}

// ---------------- QKV GEMM with fused cast: C = A_f32 @ W_bf16^T ----------------
// 128x128 tile, BK=32, 16 K-steps, 4 waves. A staged fp32 via global_load_lds
// (16KB/buf, 16B-unit XOR row&7); B staged bf16 (8KB/buf, XOR row&3).
__global__ __launch_bounds__(256) void gemm_qkv(const float* __restrict__ Aq,
                                                const float* __restrict__ Ak,
                                                const float* __restrict__ Av,
                                                const bf16* __restrict__ Wb,
                                                bf16* __restrict__ Qh,
                                                bf16* __restrict__ Kh,
                                                bf16* __restrict__ Vh) {
  __shared__ float Af[2][128*32];
  __shared__ short Bs[2][128*32];

  const int bid = blockIdx.x;               // 768 blocks
  const int xcd = bid & 7;
  const int idx = bid >> 3;                 // 0..95
  const int g   = xcd*24 + (idx >> 2);      // 0..191
  const int y   = idx & 3;
  const int z   = g >> 6;                   // 0:q 1:k 2:v
  const int m   = g & 63;

  const float* A = (z==0) ? Aq : ((z==1) ? Ak : Av);
  const bf16* Bw = Wb + (size_t)z * 262144;
  bf16* Cout     = (z==0) ? Qh : ((z==1) ? Kh : Vh);

  const int lane = threadIdx.x & 63;
  const int wid  = threadIdx.x >> 6;
  const int m0 = m * 128;
  const int n0 = y * 128;
  const int wm = (wid >> 1) * 64;
  const int wn = (wid & 1) * 64;

  const int lrowA = lane >> 3;              // 0..7
  const int luA   = lane & 7;
  const int lrowB = lane >> 2;              // 0..15
  const int luB   = lane & 3;

  const f32x4 zero4 = {0.f,0.f,0.f,0.f};
  f32x4 acc[4][4];
  for (int i=0;i<4;++i) for (int j=0;j<4;++j) acc[i][j] = zero4;

  auto stage = [&](int buf, int t) {
    const int k0 = t * 32;
    for (int i = 0; i < 4; ++i) {           // A: 16 chunks of 1KB
      int c = wid*4 + i;
      int row = c*8 + lrowA;
      gload_lds16(A + (size_t)(m0 + row)*WIDTH + k0 + ((luA ^ lrowA) * 4), &Af[buf][c*256]);
    }
    for (int i = 0; i < 2; ++i) {           // B: 8 chunks of 1KB
      int c = wid*2 + i;
      int row = c*16 + lrowB;
      gload_lds16(Bw + (size_t)(n0 + row)*WIDTH + k0 + ((luB ^ (lrowB & 3)) * 8), &Bs[buf][c*512]);
    }
  };

  stage(0, 0);
  asm volatile("s_waitcnt vmcnt(0)" ::: "memory");
  __syncthreads();
  int cur = 0;

  const int kg = lane >> 4;                 // 0..3 k-group
  for (int t = 0; t < 16; ++t) {
    if (t < 15) stage(cur ^ 1, t + 1);
    bf16x8 af[4], bfr[4];
    #pragma unroll
    for (int mf = 0; mf < 4; ++mf) {
      int row = wm + mf*16 + (lane & 15);
      const float* rp = &Af[cur][row*32];
      f32x4 lo = *(const f32x4*)(rp + (((2*kg)   ^ (row & 7)) * 4));
      f32x4 hi = *(const f32x4*)(rp + (((2*kg+1) ^ (row & 7)) * 4));
      unsigned d0 = cvtpk(lo[0], lo[1]);
      unsigned d1 = cvtpk(lo[2], lo[3]);
      unsigned d2 = cvtpk(hi[0], hi[1]);
      unsigned d3 = cvtpk(hi[2], hi[3]);
      af[mf][0] = (short)(d0 & 0xffff); af[mf][1] = (short)(d0 >> 16);
      af[mf][2] = (short)(d1 & 0xffff); af[mf][3] = (short)(d1 >> 16);
      af[mf][4] = (short)(d2 & 0xffff); af[mf][5] = (short)(d2 >> 16);
      af[mf][6] = (short)(d3 & 0xffff); af[mf][7] = (short)(d3 >> 16);
    }
    #pragma unroll
    for (int nf = 0; nf < 4; ++nf) {
      int row = wn + nf*16 + (lane & 15);
      bfr[nf] = *(const bf16x8*)(&Bs[cur][row*32 + ((kg ^ (row & 3)) * 8)]);
    }
    #pragma unroll
    for (int mf = 0; mf < 4; ++mf)
      #pragma unroll
      for (int nf = 0; nf < 4; ++nf)
        acc[mf][nf] = __builtin_amdgcn_mfma_f32_16x16x32_bf16(af[mf], bfr[nf], acc[mf][nf], 0,0,0);
    if (t < 15) {
      asm volatile("s_waitcnt vmcnt(0)" ::: "memory");
      __syncthreads();
      cur ^= 1;
    }
  }
  for (int mf=0; mf<4; ++mf)
    for (int nf=0; nf<4; ++nf) {
      int col = n0 + wn + nf*16 + (lane & 15);
      for (int r=0; r<4; ++r) {
        int row = m0 + wm + mf*16 + (lane>>4)*4 + r;
        ((unsigned short*)Cout)[(size_t)row*WIDTH + col] = f2bf(acc[mf][nf][r]);
      }
    }
}

// ---------------- output GEMM: x[8192][512] = ctx @ Wo^T, fp32 nt out ----------------
__global__ __launch_bounds__(256) void gemm_out(const bf16* __restrict__ A,
                                                const bf16* __restrict__ Bw,
                                                float* __restrict__ Cout) {
  __shared__ short As[2][128*64];
  __shared__ short Bs[2][64*64];

  const int bid = blockIdx.x;                // 512 blocks
  const int xcd = bid & 7;
  const int idx = bid >> 3;                  // 0..63
  const int m   = xcd*8 + (idx >> 3);        // 0..63
  const int y   = idx & 7;                   // 0..7 (64-col panels)

  const int lane = threadIdx.x & 63;
  const int wid  = threadIdx.x >> 6;
  const int m0 = m * 128;
  const int n0 = y * 64;
  const int wm = (wid >> 1) * 64;
  const int wn = (wid & 1) * 32;
  const int lrow = lane >> 3;
  const int swz  = ((lane & 7) ^ lrow) * 8;

  const f32x4 zero4 = {0.f,0.f,0.f,0.f};
  f32x4 acc[4][2];
  for (int i=0;i<4;++i) for (int j=0;j<2;++j) acc[i][j] = zero4;

  auto stage = [&](int buf, int t) {
    const int k0 = t * 64;
    for (int i = 0; i < 4; ++i) {
      int c = wid*4 + i;
      int row = c*8 + lrow;
      gload_lds16(A + (size_t)(m0 + row)*WIDTH + k0 + swz, &As[buf][c*512]);
    }
    for (int i = 0; i < 2; ++i) {
      int c = wid*2 + i;
      int row = c*8 + lrow;
      gload_lds16(Bw + (size_t)(n0 + row)*WIDTH + k0 + swz, &Bs[buf][c*512]);
    }
  };

  stage(0, 0);
  asm volatile("s_waitcnt vmcnt(0)" ::: "memory");
  __syncthreads();
  int cur = 0;

  for (int t = 0; t < 8; ++t) {
    if (t < 7) stage(cur ^ 1, t + 1);
    for (int kc = 0; kc < 2; ++kc) {
      bf16x8 af[4], bfr[2];
      for (int mf=0; mf<4; ++mf) af[mf]  = frag_ld(&As[cur][0], wm + mf*16 + (lane&15), (lane>>4) + kc*4);
      for (int nf=0; nf<2; ++nf) bfr[nf] = frag_ld(&Bs[cur][0], wn + nf*16 + (lane&15), (lane>>4) + kc*4);
      for (int mf=0; mf<4; ++mf)
        for (int nf=0; nf<2; ++nf)
          acc[mf][nf] = __builtin_amdgcn_mfma_f32_16x16x32_bf16(af[mf], bfr[nf], acc[mf][nf], 0,0,0);
    }
    if (t < 7) {
      asm volatile("s_waitcnt vmcnt(0)" ::: "memory");
      __syncthreads();
      cur ^= 1;
    }
  }
  for (int mf=0; mf<4; ++mf)
    for (int nf=0; nf<2; ++nf) {
      int col = n0 + wn + nf*16 + (lane & 15);
      for (int r=0; r<4; ++r) {
        int row = m0 + wm + mf*16 + (lane>>4)*4 + r;
        __builtin_nontemporal_store(acc[mf][nf][r], Cout + (size_t)row*WIDTH + col);
      }
    }
}

// ---------------- V transpose: per head (1024,64) -> (64,1024) ----------------
__global__ __launch_bounds__(256) void transpose_v(const bf16* __restrict__ Vh,
                                                   bf16* __restrict__ Vt) {
  __shared__ short t[64][72];
  int h  = blockIdx.x >> 4;
  int j0 = (blockIdx.x & 15) * 64;
  const bf16* src = Vh + (size_t)h * (SEQ*HD);
  bf16* dst = Vt + (size_t)h * (SEQ*HD);
  int tid = threadIdx.x;
  int r  = tid >> 2;
  int c0 = (tid & 3) * 16;
  bf16x8 v0 = *(const bf16x8*)(src + (size_t)(j0 + r)*HD + c0);
  bf16x8 v1 = *(const bf16x8*)(src + (size_t)(j0 + r)*HD + c0 + 8);
  for (int i = 0; i < 8; ++i) { t[r][c0+i] = v0[i]; t[r][c0+8+i] = v1[i]; }
  __syncthreads();
  bf16x8 w0, w1;
  for (int i = 0; i < 8; ++i) { w0[i] = t[c0+i][r]; w1[i] = t[c0+8+i][r]; }
  *(bf16x8*)(dst + (size_t)r*SEQ + j0 + c0)     = w0;
  *(bf16x8*)(dst + (size_t)r*SEQ + j0 + c0 + 8) = w1;
}

// ---------------- fused attention (2-pass, 8-wave, KVBLK=128, swapped QK^T) ----------------
// Block = 8 waves x 16 rows = 128 q-rows of one head; XCD-chunked (8 heads/XCD).
// KV[4] ring: pass A runs a 4-deep K pipeline (counted vmcnt 4/2/0);
// pass B uses slots {cur} for K and {2+cur} for V (== R17's Ks/Vs dbuf).
__global__ __launch_bounds__(512) void attn_kernel(const bf16* __restrict__ Qh,
                                                   const bf16* __restrict__ Kh,
                                                   const bf16* __restrict__ Vt,
                                                   float* __restrict__ attn_out,
                                                   bf16* __restrict__ ctx) {
  __shared__ short KV[4][128*64];    // 4 ring slots of 16KB
  __shared__ short Ws[8][16*64];

  const int lane = threadIdx.x & 63;
  const int wid  = threadIdx.x >> 6;         // 0..7
  const int bid  = blockIdx.x;
  const int xcd  = bid & 7;
  const int idx  = bid >> 3;                 // 0..63
  const int h    = xcd*8 + (idx >> 3);       // 8 heads/XCD
  const int i0   = (idx & 7) * 128;
  const int b  = h >> 3;
  const int nh = h & 7;

  const bf16* Qhead  = Qh + (size_t)h * (SEQ*HD);
  const bf16* Khead  = Kh + (size_t)h * (SEQ*HD);
  const bf16* Vthead = Vt + (size_t)h * (SEQ*HD);

  const int lrow = lane >> 3;
  const int swz  = ((lane & 7) ^ lrow) * 8;

  const int qrow = i0 + wid*16 + (lane & 15);
  bf16x8 qf[2];
  qf[0] = *(const bf16x8*)(Qhead + (size_t)qrow*HD + (lane>>4)*8);
  qf[1] = *(const bf16x8*)(Qhead + (size_t)qrow*HD + 32 + (lane>>4)*8);

  const f32x4 zero4 = {0.f,0.f,0.f,0.f};

  auto stageK = [&](int s, int jt) {         // 2 chunks/wave: 128 j-rows
    const int j0 = jt * 128;
    for (int i = 0; i < 2; ++i) {
      int c = wid*2 + i;                     // 0..15
      gload_lds16(Khead + (size_t)(j0 + c*8 + lrow)*HD + swz, &KV[s][c*512]);
    }
  };
  auto stageV = [&](int s, int jt) {         // 2 chunks/wave: 2 sub-tiles x 64 d-rows
    const int j0 = jt * 128;
    for (int i = 0; i < 2; ++i) {
      int c = wid*2 + i;                     // 0..15
      int sub = c >> 3, dr = (c & 7)*8 + lrow;
      gload_lds16(Vthead + (size_t)dr*SEQ + j0 + sub*64 + swz, &KV[s][c*512]);
    }
  };

  // ---- pass A: denominators, 4-deep K pipeline ----
  float lsum = 0.f;
  stageK(0, 0); stageK(1, 1); stageK(2, 2);
  asm volatile("s_waitcnt vmcnt(4)" ::: "memory");   // tile0 done
  __syncthreads();
  for (int jt = 0; jt < 8; ++jt) {
    if (jt + 3 < 8) stageK((jt + 3) & 3, jt + 3);
    const short* Kbase = &KV[jt & 3][0];
    #pragma unroll
    for (int half = 0; half < 2; ++half) {
      const short* Kt = Kbase + half*4096;
      f32x4 sac[4] = {zero4, zero4, zero4, zero4};
      __builtin_amdgcn_s_setprio(1);
      for (int kc = 0; kc < 2; ++kc)
        for (int jf = 0; jf < 4; ++jf) {
          bf16x8 kf = frag_ld(Kt, jf*16 + (lane & 15), (lane>>4) + kc*4);
          sac[jf] = __builtin_amdgcn_mfma_f32_16x16x32_bf16(kf, qf[kc], sac[jf], 0, 0, 0);
        }
      __builtin_amdgcn_s_setprio(0);
      for (int jf = 0; jf < 4; ++jf)
        for (int r = 0; r < 4; ++r)
          lsum += __expf(sac[jf][r] * SCALE_F);
    }
    if (jt < 7) {
      // counted: (tiles in flight - 1) x 2 loads must remain; next tile done
      if (jt < 5)      asm volatile("s_waitcnt vmcnt(4)" ::: "memory");
      else if (jt == 5) asm volatile("s_waitcnt vmcnt(2)" ::: "memory");
      else              asm volatile("s_waitcnt vmcnt(0)" ::: "memory");
      __builtin_amdgcn_s_barrier();
    }
  }
  lsum += __shfl_xor(lsum, 16, 64);
  lsum += __shfl_xor(lsum, 32, 64);
  const float linv = 1.0f / lsum;
  __syncthreads();

  // ---- pass B ----
  f32x4 cacc[4] = {zero4, zero4, zero4, zero4};
  short* Wsw = &Ws[wid][0];
  float* awbase = attn_out + (size_t)((size_t)h*SEQ + i0 + wid*16)*SEQ;
  stageK(0, 0); stageV(2, 0);
  asm volatile("s_waitcnt vmcnt(0)" ::: "memory");
  __syncthreads();
  int cur = 0;
  const int prow = lane & 15;                       // Ws row (i)
  const int pcb  = (lane >> 4) * 4;                 // col base within 16 (j)
  for (int jt = 0; jt < 8; ++jt) {
    if (jt < 7) { stageK(cur ^ 1, jt + 1); stageV(2 + (cur ^ 1), jt + 1); }  // 4 loads, oldest
    const int j0 = jt * 128;
    #pragma unroll
    for (int half = 0; half < 2; ++half) {
      const short* Kt  = &KV[cur][half*4096];
      const short* Vtt = &KV[2 + cur][half*4096];
      f32x4 sac[4] = {zero4, zero4, zero4, zero4};
      __builtin_amdgcn_s_setprio(1);
      for (int kc = 0; kc < 2; ++kc)
        for (int jf = 0; jf < 4; ++jf) {
          bf16x8 kf = frag_ld(Kt, jf*16 + (lane & 15), (lane>>4) + kc*4);
          sac[jf] = __builtin_amdgcn_mfma_f32_16x16x32_bf16(kf, qf[kc], sac[jf], 0, 0, 0);
        }
      __builtin_amdgcn_s_setprio(0);
      // normalized bf16 P -> Ws: per frag, 4 consecutive j -> one ds_write_b64
      #pragma unroll
      for (int jf = 0; jf < 4; ++jf) {
        float w0 = __expf(sac[jf][0] * SCALE_F) * linv;
        float w1 = __expf(sac[jf][1] * SCALE_F) * linv;
        float w2 = __expf(sac[jf][2] * SCALE_F) * linv;
        float w3 = __expf(sac[jf][3] * SCALE_F) * linv;
        uint2 pk;
        pk.x = (unsigned)f2bf(w0) | ((unsigned)f2bf(w1) << 16);
        pk.y = (unsigned)f2bf(w2) | ((unsigned)f2bf(w3) << 16);
        int colb = jf*16 + pcb;
        *(uint2*)(&Wsw[prow*64 + (((colb >> 3) ^ (prow & 7)) << 3) + (colb & 7)]) = pk;
      }
      asm volatile("s_waitcnt lgkmcnt(0)" ::: "memory");  // Ws visible; pins load<store order
      __builtin_amdgcn_s_setprio(1);
      for (int kc = 0; kc < 2; ++kc) {
        bf16x8 wa = frag_ld(Wsw, lane & 15, (lane>>4) + kc*4);
        for (int df = 0; df < 4; ++df) {
          bf16x8 vb = frag_ld(Vtt, df*16 + (lane & 15), (lane>>4) + kc*4);
          cacc[df] = __builtin_amdgcn_mfma_f32_16x16x32_bf16(wa, vb, cacc[df], 0, 0, 0);
        }
      }
      __builtin_amdgcn_s_setprio(0);
      // attn_out: 4x f32x4 non-temporal, 256B contiguous per 16-lane group
      #pragma unroll
      for (int s = 0; s < 4; ++s) {
        int row = (lane>>4) + s*4;
        int lu  = (lane & 15) >> 1;
        uint2 pv = *(const uint2*)(Wsw + row*64 + ((lu ^ (row & 7)) << 3) + (lane & 1)*4);
        f32x4 o;
        o[0] = bf2f((unsigned short)(pv.x & 0xffff));
        o[1] = bf2f((unsigned short)(pv.x >> 16));
        o[2] = bf2f((unsigned short)(pv.y & 0xffff));
        o[3] = bf2f((unsigned short)(pv.y >> 16));
        __builtin_nontemporal_store(o,
            (f32x4*)(awbase + (size_t)row*SEQ + j0 + half*64 + (lane & 15)*4));
      }
    }
    if (jt < 7) {
      asm volatile("s_waitcnt vmcnt(8) lgkmcnt(0)" ::: "memory");
      __builtin_amdgcn_s_barrier();
      cur ^= 1;
    }
  }
  for (int df = 0; df < 4; ++df)
    for (int r = 0; r < 4; ++r) {
      int irow = i0 + wid*16 + (lane>>4)*4 + r;
      ((unsigned short*)ctx)[(size_t)(b*SEQ + irow)*WIDTH + nh*HD + df*16 + (lane & 15)]
          = f2bf(cacc[df][r]);
    }
}

// ---------------- launcher ----------------
extern "C" void kernel_launch(void* const* d_in, const int* in_sizes, int n_in,
                              void* d_out, int out_size, void* d_ws, size_t ws_size,
                              hipStream_t stream) {
  const float* q  = (const float*)d_in[0];
  const float* k  = (const float*)d_in[1];
  const float* v  = (const float*)d_in[2];
  const float* wq = (const float*)d_in[3];
  const float* wk = (const float*)d_in[4];
  const float* wv = (const float*)d_in[5];
  const float* wo = (const float*)d_in[6];

  bf16* wsb = (bf16*)d_ws;
  bf16* wqb = wsb;                      // 4 x 262144 (wq,wk,wv,wo)
  bf16* wob = wqb + 3*262144;
  bf16* Qh  = wqb + 4*262144;
  bf16* Kh  = Qh + 4194304;
  bf16* Vh  = Kh + 4194304;
  bf16* Vt  = Vh + 4194304;
  bf16* ctx = Vt + 4194304;

  float* x_out    = (float*)d_out;             // (8,1024,512)
  float* attn_out = (float*)d_out + 4194304;   // (8,8,1024,1024)

  wcast_kernel<<<1024, 256, 0, stream>>>(wq, wk, wv, wo, wqb);
  gemm_qkv<<<768, 256, 0, stream>>>(q, k, v, wqb, Qh, Kh, Vh);
  transpose_v<<<1024, 256, 0, stream>>>(Vh, Vt);
  attn_kernel<<<512, 512, 0, stream>>>(Qh, Kh, Vt, attn_out, ctx);
  gemm_out<<<512, 256, 0, stream>>>(ctx, wob, x_out);
}